// Round 9
// baseline (3440.062 us; speedup 1.0000x reference)
//
#include <hip/hip_runtime.h>

typedef _Float16 f16;
typedef _Float16 f16x4 __attribute__((ext_vector_type(4)));
typedef _Float16 f16x8 __attribute__((ext_vector_type(8)));
typedef __fp16   fp16x2 __attribute__((ext_vector_type(2)));
typedef float    f32x4 __attribute__((ext_vector_type(4)));

#define MFMA_F16(A,B,C) __builtin_amdgcn_mfma_f32_16x16x32_f16((A),(B),(C),0,0,0)

// 2*log2(e): pre-activation is stored pre-scaled by this, so tanh(z) needs only
// exp2: z2 = acc*C2 + preC;  tanh = 1 - 2*rcp(exp2(z2)+1)
#define C2F 2.885390081777927f

// pack 4 floats -> f16x4 via two v_cvt_pkrtz_f16_f32 (bit-identical reinterpret)
__device__ __forceinline__ f16x4 pk4(float a, float b, float c, float d) {
  union { fp16x2 p[2]; f16x4 v; } u;
  u.p[0] = __builtin_amdgcn_cvt_pkrtz(a, b);
  u.p[1] = __builtin_amdgcn_cvt_pkrtz(c, d);
  return u.v;
}

// Physical LDS slot permutation: spreads the b64-write bank pattern while the
// b128 read side stays a bijective slot permutation => conflict-free reads.
__device__ __forceinline__ int pslot(int s) {
  return s ^ (((s >> 3) & 1) << 2) ^ (((s >> 4) & 1) << 1);
}

// Global fragment-pack layout P for pre0 (f16):
//   elem(t, b, col) -> t*16384 + (col>>2)*256 + b*4 + (col&3)

// ---------------------------------------------------------------------------
// prep: weights fp32 -> fp16 (row-major), biases combined AND scaled by C2
// ---------------------------------------------------------------------------
__global__ void prep_kernel(const float* __restrict__ Wih0, const float* __restrict__ Whh0,
                            const float* __restrict__ Wih1, const float* __restrict__ Whh1,
                            const float* __restrict__ bih0, const float* __restrict__ bhh0,
                            const float* __restrict__ bih1, const float* __restrict__ bhh1,
                            f16* __restrict__ wdst, float* __restrict__ b0C, float* __restrict__ b1C)
{
  if (blockIdx.x == 224) {
    const int i = threadIdx.x;  // 256 threads
    b0C[i] = (bih0[i] + bhh0[i]) * C2F;
    b1C[i] = (bih1[i] + bhh1[i]) * C2F;
    return;
  }
  const int i4 = (blockIdx.x * 256 + threadIdx.x) * 4;
  const float* src; int off;
  if (i4 < 32768)       { src = Wih0; off = i4; }
  else if (i4 < 98304)  { src = Whh0; off = i4 - 32768; }
  else if (i4 < 163840) { src = Wih1; off = i4 - 98304; }
  else                  { src = Whh1; off = i4 - 163840; }
  const float4 v = *(const float4*)(src + off);
  *(f16x4*)(wdst + i4) = pk4(v.x, v.y, v.z, v.w);
}

// ---------------------------------------------------------------------------
// gemm_proj<128,0>: preC0 = (x @ Wih0^T + b0) * C2, P layout (f16).
// x fp32 [64 b][2048 t][128]; block = (b, 64-t tile).
// Per WG: 64 rows x 256 outcols, 4 waves; wave wv owns outcols [wv*64,+64)
// ---------------------------------------------------------------------------
__global__ __launch_bounds__(256, 2)
void gemm_proj0(const float* __restrict__ x, const f16* __restrict__ W,
                const float* __restrict__ biasC, f16* __restrict__ outp)
{
  constexpr int NKB = 4;  // K=128
  __shared__ f16 sB[4 * NKB * 512];  // [rt 0..3][kb][slot 0..63][j8]

  const int tid = threadIdx.x, lane = tid & 63, wv = tid >> 6;
  const int l15 = lane & 15, l4 = lane >> 4;
  const int bid = blockIdx.x;

  {
    const float* xp = x + ((size_t)(bid >> 5) * 2048 + (size_t)(bid & 31) * 64) * 128;
    const int rp = tid >> 3, kg = tid & 7;
#pragma unroll
    for (int rr = 0; rr < 2; ++rr) {
      const int row = rp * 2 + rr;
      const float* xr = xp + (size_t)row * 128 + kg * 16;
#pragma unroll
      for (int c4 = 0; c4 < 4; ++c4) {
        const float4 v = *(const float4*)(xr + c4 * 4);
        const int k = kg * 16 + c4 * 4;
        const int rt = row >> 4, kb = k >> 5;
        const int slot = (row & 15) + 16 * ((k >> 3) & 3);
        *(f16x4*)&sB[rt * (NKB * 512) + kb * 512 + slot * 8 + (k & 7)] = pk4(v.x, v.y, v.z, v.w);
      }
    }
  }
  __syncthreads();

  f16x8 wa[4][NKB];
#pragma unroll
  for (int ct = 0; ct < 4; ++ct) {
    const int oc = wv * 64 + ct * 16 + l15;
#pragma unroll
    for (int kb = 0; kb < NKB; ++kb)
      wa[ct][kb] = *(const f16x8*)(W + (size_t)oc * 128 + kb * 32 + l4 * 8);
  }
  float bC[4][4];
#pragma unroll
  for (int ct = 0; ct < 4; ++ct)
#pragma unroll
    for (int r = 0; r < 4; ++r)
      bC[ct][r] = biasC[wv * 64 + ct * 16 + l4 * 4 + r];

  f32x4 acc[4][4];
#pragma unroll
  for (int ct = 0; ct < 4; ++ct)
#pragma unroll
    for (int rt = 0; rt < 4; ++rt)
      acc[ct][rt] = f32x4{0.f, 0.f, 0.f, 0.f};

#pragma unroll
  for (int kb = 0; kb < NKB; ++kb)
#pragma unroll
    for (int rt = 0; rt < 4; ++rt) {
      const f16x8 hb = *(const f16x8*)&sB[rt * (NKB * 512) + kb * 512 + lane * 8];
#pragma unroll
      for (int ct = 0; ct < 4; ++ct)
        acc[ct][rt] = MFMA_F16(wa[ct][kb], hb, acc[ct][rt]);
    }

#pragma unroll
  for (int rt = 0; rt < 4; ++rt) {
    const int rown = rt * 16 + l15;
    const size_t base = ((size_t)(bid & 31) * 64 + rown) * 16384 + (size_t)(bid >> 5) * 4;
#pragma unroll
    for (int ct = 0; ct < 4; ++ct) {
      const int cp = wv * 16 + ct * 4 + l4;
      const float v0 = fmaf(acc[ct][rt][0], C2F, bC[ct][0]);
      const float v1 = fmaf(acc[ct][rt][1], C2F, bC[ct][1]);
      const float v2 = fmaf(acc[ct][rt][2], C2F, bC[ct][2]);
      const float v3 = fmaf(acc[ct][rt][3], C2F, bC[ct][3]);
      *(f16x4*)(outp + base + (size_t)cp * 256) = pk4(v0, v1, v2, v3);
    }
  }
}

// ---------------------------------------------------------------------------
// fused_rnn: BOTH layers in one sequential kernel, layer-1 lagging by 1 tick.
// 4 WGs x 16 batches x 8 waves (2 waves/SIMD); wave owns 32 outcols.
// Tick t: h0[t] = tanh(pre0[t] + Whh0 h0[t-1]);  h1[t-1] = tanh(Wih1 h0[t-1]
// + Whh1 h1[t-2] + b1).  The h0[t-1] LDS fragments are read ONCE and feed
// both the Whh0 and Wih1 MFMAs (register reuse).  h0/h1 live only in LDS
// (double-buffered fragment layouts, 32KB); 3 weight sets VGPR-resident
// (192 VGPRs).  One s_barrier per tick, lgkmcnt-only drain (pre0 prefetch
// stays in flight).  2049 ticks total; h1[2047] -> hlast (f32) at the end.
// ---------------------------------------------------------------------------
__global__ __launch_bounds__(512, 2)
void fused_rnn(const f16* __restrict__ pre,   // P layout [T][cp][b][4], pre-scaled
               const f16* __restrict__ Whh0,  // [256][256] f16 row-major
               const f16* __restrict__ Wih1,
               const f16* __restrict__ Whh1,
               const float* __restrict__ b1C, // (bih1+bhh1)*C2
               float* __restrict__ hlast)     // [64][256] f32
{
  __shared__ f16 sH[16384];  // h0: [0,4096),[4096,8192); h1: [8192,12288),[12288,16384)
  const int tid = threadIdx.x, lane = tid & 63, wv = tid >> 6;  // wv 0..7
  const int l15 = lane & 15, l4 = lane >> 4;
  const int g16 = blockIdx.x * 16;

  // zero h0buf0 (ticks 0 reads) and both h1 bufs (tick1 reads h1buf1 = h1[-1])
  for (int i = tid; i < 2048; i += 512) ((unsigned int*)sH)[i] = 0u;
  for (int i = tid; i < 4096; i += 512) ((unsigned int*)sH)[4096 + i] = 0u;

  // A-frags (3 sets, VGPR-resident): lane holds W[wv*32+ct*16+l15][kb*32+l4*8..+7]
  f16x8 wa0[2][8], wi1[2][8], wh1[2][8];
#pragma unroll
  for (int ct = 0; ct < 2; ++ct) {
    const size_t oc = (size_t)(wv * 32 + ct * 16 + l15) * 256;
#pragma unroll
    for (int kb = 0; kb < 8; ++kb) {
      wa0[ct][kb] = *(const f16x8*)(Whh0 + oc + kb * 32 + l4 * 8);
      wi1[ct][kb] = *(const f16x8*)(Wih1 + oc + kb * 32 + l4 * 8);
      wh1[ct][kb] = *(const f16x8*)(Whh1 + oc + kb * 32 + l4 * 8);
    }
  }
  float b1r[2][4];
#pragma unroll
  for (int ct = 0; ct < 2; ++ct)
#pragma unroll
    for (int r = 0; r < 4; ++r)
      b1r[ct][r] = b1C[wv * 32 + ct * 16 + l4 * 4 + r];

  // LDS write offsets within a buffer (wave's cols form kb block wv)
  int woff[2];
#pragma unroll
  for (int ct = 0; ct < 2; ++ct) {
    const int q = ct * 2 + (l4 >> 1);
    woff[ct] = wv * 512 + pslot(l15 + 16 * q) * 8 + (l4 & 1) * 4;
  }
  const int roff = pslot(lane) * 8;

  // global P lane offset for pre0: cp = wv*8 + ct*4 + l4, b = g16+l15
  const int laneP = (wv * 8 + l4) * 256 + (g16 + l15) * 4;  // + ct*1024 + t*16384

  f16x4 pA[2], pB[2];
#pragma unroll
  for (int ct = 0; ct < 2; ++ct) {
    pA[ct] = *(const f16x4*)(pre + laneP + ct * 1024);
    pB[ct] = *(const f16x4*)(pre + 16384 + laneP + ct * 1024);
  }
  __syncthreads();

  auto tick = [&](int t, int h0r, int h0w, int h1r, int h1w, f16x4 (&pc)[2]) {
    f32x4 a0[2], a1[2];
#pragma unroll
    for (int i = 0; i < 2; ++i) { a0[i] = f32x4{0.f,0.f,0.f,0.f}; a1[i] = f32x4{0.f,0.f,0.f,0.f}; }
    // h0[t-1] frags: read once, feed Whh0 (layer0) AND Wih1 (layer1)
#pragma unroll
    for (int kb = 0; kb < 8; ++kb) {
      const f16x8 hb = *(const f16x8*)&sH[h0r + kb * 512 + roff];
      a0[0] = MFMA_F16(wa0[0][kb], hb, a0[0]);
      a0[1] = MFMA_F16(wa0[1][kb], hb, a0[1]);
      a1[0] = MFMA_F16(wi1[0][kb], hb, a1[0]);
      a1[1] = MFMA_F16(wi1[1][kb], hb, a1[1]);
    }
    // h1[t-2] frags
#pragma unroll
    for (int kb = 0; kb < 8; ++kb) {
      const f16x8 hb = *(const f16x8*)&sH[h1r + kb * 512 + roff];
      a1[0] = MFMA_F16(wh1[0][kb], hb, a1[0]);
      a1[1] = MFMA_F16(wh1[1][kb], hb, a1[1]);
    }
    // layer0 epilogue: z = a0*C2 + pre0C[t]; then prefetch pre0[t+2]
    float z0[2][4];
#pragma unroll
    for (int ct = 0; ct < 2; ++ct)
#pragma unroll
      for (int r = 0; r < 4; ++r)
        z0[ct][r] = fmaf(a0[ct][r], C2F, (float)pc[ct][r]);
    if (t + 2 < 2048) {
#pragma unroll
      for (int ct = 0; ct < 2; ++ct)
        pc[ct] = *(const f16x4*)(pre + (size_t)(t + 2) * 16384 + laneP + ct * 1024);
    }
#pragma unroll
    for (int ct = 0; ct < 2; ++ct) {
      float h[4];
#pragma unroll
      for (int r = 0; r < 4; ++r) {
        const float e = __builtin_amdgcn_exp2f(z0[ct][r]);
        h[r] = fmaf(__builtin_amdgcn_rcpf(e + 1.0f), -2.0f, 1.0f);
      }
      *(f16x4*)&sH[h0w + woff[ct]] = pk4(h[0], h[1], h[2], h[3]);
    }
    // layer1 epilogue: h1[t-1] = tanh-from-exp2(a1*C2 + b1C); skip write at t=0
#pragma unroll
    for (int ct = 0; ct < 2; ++ct) {
      float h[4];
#pragma unroll
      for (int r = 0; r < 4; ++r) {
        const float e = __builtin_amdgcn_exp2f(fmaf(a1[ct][r], C2F, b1r[ct][r]));
        h[r] = fmaf(__builtin_amdgcn_rcpf(e + 1.0f), -2.0f, 1.0f);
      }
      if (t > 0) *(f16x4*)&sH[h1w + woff[ct]] = pk4(h[0], h[1], h[2], h[3]);
    }
    // LDS-only drain before barrier: pre0 prefetch loads stay in flight
    asm volatile("s_waitcnt lgkmcnt(0)" ::: "memory");
    __builtin_amdgcn_sched_barrier(0);
    __builtin_amdgcn_s_barrier();
    __builtin_amdgcn_sched_barrier(0);
  };

#pragma unroll 1
  for (int t = 0; t < 2048; t += 2) {
    tick(t,     0,    4096, 8192,  12288, pA);   // even: h0 r0/w1, h1 r0/w1
    tick(t + 1, 4096, 0,    12288, 8192,  pB);   // odd:  h0 r1/w0, h1 r1/w0
  }

  // final tick t=2048: layer1 only -> h1[2047] = tanh(Wih1 h0[2047] + Whh1 h1[2046] + b1)
  {
    f32x4 a1[2];
#pragma unroll
    for (int i = 0; i < 2; ++i) a1[i] = f32x4{0.f,0.f,0.f,0.f};
#pragma unroll
    for (int kb = 0; kb < 8; ++kb) {
      const f16x8 hb = *(const f16x8*)&sH[0 + kb * 512 + roff];      // h0[2047]
      a1[0] = MFMA_F16(wi1[0][kb], hb, a1[0]);
      a1[1] = MFMA_F16(wi1[1][kb], hb, a1[1]);
    }
#pragma unroll
    for (int kb = 0; kb < 8; ++kb) {
      const f16x8 hb = *(const f16x8*)&sH[8192 + kb * 512 + roff];   // h1[2046]
      a1[0] = MFMA_F16(wh1[0][kb], hb, a1[0]);
      a1[1] = MFMA_F16(wh1[1][kb], hb, a1[1]);
    }
#pragma unroll
    for (int ct = 0; ct < 2; ++ct)
#pragma unroll
      for (int r = 0; r < 4; ++r) {
        const float e = __builtin_amdgcn_exp2f(fmaf(a1[ct][r], C2F, b1r[ct][r]));
        const float h = fmaf(__builtin_amdgcn_rcpf(e + 1.0f), -2.0f, 1.0f);
        hlast[(g16 + l15) * 256 + wv * 32 + ct * 16 + l4 * 4 + r] = h;
      }
  }
}

// ---------------------------------------------------------------------------
// fc: out[b][o] = h2last[b] . fc_w[o] + fc_b[o]
// ---------------------------------------------------------------------------
__global__ void fc_kernel(const float* __restrict__ h, const float* __restrict__ W,
                          const float* __restrict__ bvec, float* __restrict__ out)
{
  const int idx = blockIdx.x * 256 + threadIdx.x;  // 8192
  const int bb = idx >> 7, o = idx & 127;
  const float4* hp = (const float4*)(h + bb * 256);
  const float4* wp = (const float4*)(W + o * 256);
  float acc = 0.f;
#pragma unroll
  for (int i = 0; i < 64; ++i) {
    const float4 a = hp[i], c = wp[i];
    acc += a.x * c.x + a.y * c.y + a.z * c.z + a.w * c.w;
  }
  out[idx] = acc + bvec[o];
}

// ---------------------------------------------------------------------------
extern "C" void kernel_launch(void* const* d_in, const int* in_sizes, int n_in,
                              void* d_out, int out_size, void* d_ws, size_t ws_size,
                              hipStream_t stream)
{
  const float* x    = (const float*)d_in[0];
  const float* Wih0 = (const float*)d_in[1];
  const float* Whh0 = (const float*)d_in[2];
  const float* bih0 = (const float*)d_in[3];
  const float* bhh0 = (const float*)d_in[4];
  const float* Wih1 = (const float*)d_in[5];
  const float* Whh1 = (const float*)d_in[6];
  const float* bih1 = (const float*)d_in[7];
  const float* bhh1 = (const float*)d_in[8];
  const float* fcw  = (const float*)d_in[9];
  const float* fcb  = (const float*)d_in[10];
  float* out = (float*)d_out;

  // Workspace plan (~64.5 MB total)
  char* ws = (char*)d_ws;
  f16*   Wih0h  = (f16*)(ws);             // 64 KB (base for all 4 matrices)
  f16*   Whh0h  = (f16*)(ws + 65536);     // 128 KB
  f16*   Wih1h  = (f16*)(ws + 196608);    // 128 KB
  f16*   Whh1h  = (f16*)(ws + 327680);    // 128 KB
  float* b0C    = (float*)(ws + 458752);  // 1 KB
  float* b1C    = (float*)(ws + 459776);  // 1 KB
  float* h2last = (float*)(ws + 460800);  // 64 KB
  f16*   buf    = (f16*)(ws + 526336);    // 64 MiB: pre0 (read-only in fused_rnn)

  prep_kernel<<<225, 256, 0, stream>>>(Wih0, Whh0, Wih1, Whh1, bih0, bhh0, bih1, bhh1,
                                       Wih0h, b0C, b1C);
  gemm_proj0<<<2048, 256, 0, stream>>>(x, Wih0h, b0C, buf);              // preC0 (P layout)
  fused_rnn<<<4, 512, 0, stream>>>(buf, Whh0h, Wih1h, Whh1h, b1C, h2last);
  fc_kernel<<<32, 256, 0, stream>>>(h2last, fcw, fcb, out);
}